// Round 21
// baseline (48.689 us; speedup 1.0000x reference)
//
#include <hip/hip_runtime.h>
#include <math.h>

#define N 4096
#define D 128
#define NROW 16
#define NPAN 256              // row panels
#define NBLK2 512             // 2 blocks per panel
#define BIGV 1e30f
#define E1C  2.718281828459045f
#define EM5C 0.006737946999085467f
#define AUXW (5 * N + 769)    // minE,maxE,possum,negsum,cntsum (5N) + lpart(256)+pcnt(256)+fcnt(256)+done(1)

typedef __bf16 bf16x8 __attribute__((ext_vector_type(8)));
typedef float  f32x4  __attribute__((ext_vector_type(4)));

__device__ __forceinline__ void stg(float* p, float v) {
  __hip_atomic_store(p, v, __ATOMIC_RELAXED, __HIP_MEMORY_SCOPE_AGENT);
}
__device__ __forceinline__ float ldg1(const float* p) {
  return __hip_atomic_load((float*)p, __ATOMIC_RELAXED, __HIP_MEMORY_SCOPE_AGENT);
}
__device__ __forceinline__ unsigned ldu(const unsigned* p) {
  return __hip_atomic_load((unsigned*)p, __ATOMIC_RELAXED, __HIP_MEMORY_SCOPE_AGENT);
}
// monotone IEEE key (bijective): max via enc-atomicMax; min via ~enc-atomicMax (0 = empty)
__device__ __forceinline__ unsigned enc(float f) {
  unsigned u = __float_as_uint(f);
  return (u & 0x80000000u) ? ~u : (u | 0x80000000u);
}
__device__ __forceinline__ float dec(unsigned k) {
  unsigned u = (k & 0x80000000u) ? (k & 0x7FFFFFFFu) : ~k;
  return __uint_as_float(u);
}

__device__ __forceinline__ void cvt8(float4 v0, float4 v1, int4& hp, int4& lp) {
  float vf[8] = {v0.x, v0.y, v0.z, v0.w, v1.x, v1.y, v1.z, v1.w};
  unsigned h[8], l[8];
#pragma unroll
  for (int i = 0; i < 8; ++i) {
    unsigned u = __float_as_uint(vf[i]);
    unsigned hr = (u + 0x7FFFu + ((u >> 16) & 1u)) >> 16;
    float hv = __uint_as_float(hr << 16);
    unsigned ul = __float_as_uint(vf[i] - hv);
    l[i] = (ul + 0x7FFFu + ((ul >> 16) & 1u)) >> 16;
    h[i] = hr;
  }
  hp = make_int4((int)(h[0] | (h[1] << 16)), (int)(h[2] | (h[3] << 16)),
                 (int)(h[4] | (h[5] << 16)), (int)(h[6] | (h[7] << 16)));
  lp = make_int4((int)(l[0] | (l[1] << 16)), (int)(l[2] | (l[3] << 16)),
                 (int)(l[4] | (l[5] << 16)), (int)(l[6] | (l[7] << 16)));
}
__device__ __forceinline__ void cvt8hi(float4 v0, float4 v1, int4& hp) {
  float vf[8] = {v0.x, v0.y, v0.z, v0.w, v1.x, v1.y, v1.z, v1.w};
  unsigned h[8];
#pragma unroll
  for (int i = 0; i < 8; ++i) {
    unsigned u = __float_as_uint(vf[i]);
    h[i] = (u + 0x7FFFu + ((u >> 16) & 1u)) >> 16;
  }
  hp = make_int4((int)(h[0] | (h[1] << 16)), (int)(h[2] | (h[3] << 16)),
                 (int)(h[4] | (h[5] << 16)), (int)(h[6] | (h[7] << 16)));
}

// x -> bf16-hi fragment-linear; also zero the aux region (atomics/counters/sums)
__global__ __launch_bounds__(256)
void k_conv(const float* __restrict__ x, ushort* __restrict__ xf, unsigned* __restrict__ aux)
{
  int gid = blockIdx.x * 256 + threadIdx.x;     // 65536 threads
  if (gid < AUXW) aux[gid] = 0u;
  int C = gid >> 4, k16 = gid & 15;
  const float* ap = x + C * D + k16 * 8;
  float4 v0 = *(const float4*)ap, v1 = *(const float4*)(ap + 4);
  int4 hp;
  cvt8hi(v0, v1, hp);
  int unit = ((C >> 4) * 4 + (k16 >> 2)) * 64 + (k16 & 3) * 16 + (C & 15);
  *(int4*)((char*)xf + ((size_t)unit << 4)) = hp;
}

// 512 blocks x 1024 threads; block b: panel P=b>>1 (rows 16P..16P+15), half H=b&1
// (col-tiles [H*128 + w*8, +8) per wave w). Transposed attribution: lane owns ONE row.
__global__ __launch_bounds__(1024, 8)
void k_main(const float* __restrict__ x, const int* __restrict__ tgt,
            const float* __restrict__ marg, const float* __restrict__ wgt,
            const int* __restrict__ hm, float* __restrict__ out,
            const ushort* __restrict__ xf,
            unsigned* __restrict__ minE, unsigned* __restrict__ maxE,
            float* __restrict__ possum, float* __restrict__ negsum,
            float* __restrict__ cntsum, float* __restrict__ lpart,
            unsigned* __restrict__ pcnt, unsigned* __restrict__ fcnt,
            unsigned* __restrict__ done)
{
  __shared__ char AhL[4096], AlL[4096];              // 16 rows x 128 k bf16, XOR-swizzled
  __shared__ float redA[16][16], redB[16][16], redC[16][16];
  __shared__ float finMn[16], finMx[16], lsRow[16], lsum[16];
  __shared__ unsigned lastf, lastd;

  const int tid = threadIdx.x;
  const int bid = blockIdx.x;
  const int w = tid >> 6, l = tid & 63;
  const int c = l & 15, g = l >> 4;
  const int P = bid >> 1, H = bid & 1;
  const int i0 = P * NROW;
  const int ctb = H * 128 + w * 8;

  // ---- stage panel A (hi+lo) into block LDS, swizzled: unit' = k16 ^ (row&7) ----
  if (tid < 256) {
    int row = tid >> 4, k16 = tid & 15;
    const float* ap = x + (i0 + row) * D + k16 * 8;
    float4 v0 = *(const float4*)ap, v1 = *(const float4*)(ap + 4);
    int4 hp, lp;
    cvt8(v0, v1, hp, lp);
    int off = row * 256 + ((k16 ^ (row & 7)) << 4);
    *(int4*)&AhL[off] = hp;
    *(int4*)&AlL[off] = lp;
  }
  const int trg = tgt[i0 + c];
  __syncthreads();

  // ---- GEMM + fused pass-1 scan (scalar row state), persistent acc[8] ----
  f32x4 acc[8];
  float mn = BIGV, mx = -BIGV;
#pragma unroll
  for (int ci = 0; ci < 8; ++ci) {
    const int ct = ctb + ci;
    f32x4 a = f32x4{0.f, 0.f, 0.f, 0.f};
    if (ct == P) {
#pragma unroll
      for (int kt = 0; kt < 4; ++kt) {
        int off = c * 256 + (((kt * 4 + g) ^ (c & 7)) << 4);
        bf16x8 ah = *(const bf16x8*)&AhL[off];
        bf16x8 al = *(const bf16x8*)&AlL[off];
        a = __builtin_amdgcn_mfma_f32_16x16x32_bf16(ah, ah, a, 0, 0, 0);
        a = __builtin_amdgcn_mfma_f32_16x16x32_bf16(ah, al, a, 0, 0, 0);
        a = __builtin_amdgcn_mfma_f32_16x16x32_bf16(al, ah, a, 0, 0, 0);
      }
    } else {
      const char* bp = (const char*)xf + (((size_t)ct * 256 + l) << 4);
#pragma unroll
      for (int kt = 0; kt < 4; ++kt) {
        bf16x8 Bh = *(const bf16x8*)(bp + (kt << 10));
        int off = c * 256 + (((kt * 4 + g) ^ (c & 7)) << 4);
        bf16x8 ah = *(const bf16x8*)&AhL[off];
        bf16x8 al = *(const bf16x8*)&AlL[off];
        a = __builtin_amdgcn_mfma_f32_16x16x32_bf16(Bh, ah, a, 0, 0, 0);
        a = __builtin_amdgcn_mfma_f32_16x16x32_bf16(Bh, al, a, 0, 0, 0);
      }
    }
    acc[ci] = a;
#pragma unroll
    for (int jj = 0; jj < 4; ++jj) {
      float s = a[jj];
      int tc = tgt[ct * 16 + g * 4 + jj];
      if (tc == trg) { if (s < 1.0f) mn = fminf(mn, s); }
      else             mx = fmaxf(mx, s);
    }
    __builtin_amdgcn_sched_barrier(0);   // bound load hoisting (anti-spill)
  }

  // ---- reduce min/max: g-groups then waves, then global panel atomics ----
  mn = fminf(mn, __shfl_xor(mn, 16, 64));
  mn = fminf(mn, __shfl_xor(mn, 32, 64));
  mx = fmaxf(mx, __shfl_xor(mx, 16, 64));
  mx = fmaxf(mx, __shfl_xor(mx, 32, 64));
  if (l < 16) { redA[w][c] = mn; redB[w][c] = mx; }
  __syncthreads();
  if (tid < 16) {
    float a0 = BIGV, b0 = -BIGV;
#pragma unroll
    for (int w16 = 0; w16 < 16; ++w16) {
      a0 = fminf(a0, redA[w16][tid]);
      b0 = fmaxf(b0, redB[w16][tid]);
    }
    if (a0 <  BIGV) atomicMax(&minE[i0 + tid], ~enc(a0));
    if (b0 > -BIGV) atomicMax(&maxE[i0 + tid], enc(b0));
  }
  __syncthreads();                       // drains the atomics (vmcnt before barrier)
  if (tid == 0) {
    atomicAdd(&pcnt[P], 1u);
    while (ldu(&pcnt[P]) < 2u) __builtin_amdgcn_s_sleep(2);
  }
  __syncthreads();
  if (tid < 16) {
    unsigned kmin = ldu(&minE[i0 + tid]);
    unsigned kmax = ldu(&maxE[i0 + tid]);
    finMn[tid] = (kmin == 0u) ?  BIGV : dec(~kmin);
    finMx[tid] = (kmax == 0u) ? -BIGV : dec(kmax);
  }
  __syncthreads();

  // ---- mining over persistent acc (merged thresholds, factored exp) ----
  const int mode = hm[0];
  float thrP, thrN, wp, wn;
  {
    float mg = marg[i0 + c], wt = wgt[i0 + c];
    if (mode == 1) {
      thrP = fminf(1.0f, finMx[c] + mg);
      thrN = finMn[c] - mg;
      wp = -2.f * wt; wn = 10.f * wt;
    } else {
      thrP = 1.0f; thrN = -BIGV;
      wp = -2.f; wn = 10.f;
    }
  }
  float ps = 0.f, ns = 0.f, cnt = 0.f;   // cnt = ap + 4096*an (exact)
#pragma unroll
  for (int ci = 0; ci < 8; ++ci) {
    const int ct = ctb + ci;
#pragma unroll
    for (int jj = 0; jj < 4; ++jj) {
      float s = acc[ci][jj];
      int tc = tgt[ct * 16 + g * 4 + jj];
      if (tc == trg) {
        if (s < thrP) { ps += __expf(wp * s); cnt += 1.f; }
      } else {
        if (s > thrN) { ns += __expf(wn * s); cnt += 4096.f; }
      }
    }
  }
  ps  += __shfl_xor(ps, 16, 64);  ps  += __shfl_xor(ps, 32, 64);
  ns  += __shfl_xor(ns, 16, 64);  ns  += __shfl_xor(ns, 32, 64);
  cnt += __shfl_xor(cnt, 16, 64); cnt += __shfl_xor(cnt, 32, 64);
  if (l < 16) { redA[w][c] = ps; redB[w][c] = ns; redC[w][c] = cnt; }
  __syncthreads();
  if (tid < 16) {
    float tps = 0.f, tns = 0.f, tcnt = 0.f;
#pragma unroll
    for (int w16 = 0; w16 < 16; ++w16) {
      tps += redA[w16][tid]; tns += redB[w16][tid]; tcnt += redC[w16][tid];
    }
    if (tps  != 0.f) atomicAdd(&possum[i0 + tid], tps);
    if (tns  != 0.f) atomicAdd(&negsum[i0 + tid], tns);
    if (tcnt != 0.f) atomicAdd(&cntsum[i0 + tid], tcnt);
  }
  __syncthreads();                       // drains sum atomics
  if (tid == 0) {
    unsigned o = __hip_atomic_fetch_add(&fcnt[P], 1u, __ATOMIC_ACQ_REL, __HIP_MEMORY_SCOPE_AGENT);
    lastf = (o == 1u) ? 1u : 0u;
  }
  __syncthreads();

  // ---- panel finalizer (dataflow: 2nd block of the pair) ----
  if (lastf) {
    if (tid < 16) {
      float tps = ldg1(&possum[i0 + tid]);
      float tns = ldg1(&negsum[i0 + tid]);
      float tcnt = ldg1(&cntsum[i0 + tid]);
      float an = floorf(tcnt * (1.0f / 4096.0f));
      float ap = tcnt - an * 4096.0f;
      float mg = marg[i0 + tid];
      float sP = (mode == 1) ? E1C  : __expf(1.f + 2.f * mg);
      float sN = (mode == 1) ? EM5C : __expf(-5.f + 10.f * mg);
      float loss_i = log1pf(tps * sP) + 0.2f * log1pf(tns * sN);
      if (mode == 1 && (ap + an) < 1.0f) { loss_i = 0.f; ap = 0.f; an = 0.f; }
      out[1 + i0 + tid]     = ap;
      out[1 + N + i0 + tid] = an;
      lsRow[tid] = loss_i;
    }
    __syncthreads();
    if (tid == 0) {
      float lb = 0.f;
#pragma unroll
      for (int r = 0; r < 16; ++r) lb += lsRow[r];
      stg(&lpart[P], lb);
      asm volatile("s_waitcnt vmcnt(0)" ::: "memory");
      unsigned o2 = __hip_atomic_fetch_add(done, 1u, __ATOMIC_ACQ_REL, __HIP_MEMORY_SCOPE_AGENT);
      lastd = (o2 == (unsigned)(NPAN - 1)) ? 1u : 0u;
    }
    __syncthreads();
    // last finalizer sums the 256 loss partials block-parallel
    if (lastd) {
      float v = (tid < NPAN) ? ldg1(&lpart[tid]) : 0.f;
#pragma unroll
      for (int msk = 32; msk; msk >>= 1) v += __shfl_down(v, msk, 64);
      if ((tid & 63) == 0) lsum[tid >> 6] = v;
      __syncthreads();
      if (tid == 0) {
        float s = 0.f;
#pragma unroll
        for (int k2 = 0; k2 < 4; ++k2) s += lsum[k2];   // only waves 0-3 held data
        out[0] = s / (float)N;
      }
    }
  }
}

extern "C" void kernel_launch(void* const* d_in, const int* in_sizes, int n_in,
                              void* d_out, int out_size, void* d_ws, size_t ws_size,
                              hipStream_t stream)
{
  (void)in_sizes; (void)n_in; (void)out_size; (void)ws_size;
  const float* x    = (const float*)d_in[0];
  const int*   tgt  = (const int*)d_in[1];
  const float* marg = (const float*)d_in[2];
  const float* wgt  = (const float*)d_in[3];
  const int*   hm   = (const int*)d_in[4];
  float* out = (float*)d_out;

  ushort*   xf     = (ushort*)d_ws;                    // 1 MB fragment-linear bf16-hi
  unsigned* aux    = (unsigned*)((char*)d_ws + (1 << 20));
  unsigned* minE   = aux;                              // N
  unsigned* maxE   = minE + N;                         // N
  float*    possum = (float*)(maxE + N);               // N
  float*    negsum = possum + N;                       // N
  float*    cntsum = negsum + N;                       // N
  float*    lpart  = cntsum + N;                       // 256
  unsigned* pcnt   = (unsigned*)(lpart + NPAN);        // 256
  unsigned* fcnt   = pcnt + NPAN;                      // 256
  unsigned* done   = fcnt + NPAN;                      // 1

  k_conv<<<256, 256, 0, stream>>>(x, xf, aux);
  k_main<<<NBLK2, 1024, 0, stream>>>(x, tgt, marg, wgt, hm, out, xf,
                                     minE, maxE, possum, negsum, cntsum,
                                     lpart, pcnt, fcnt, done);
}

// Round 22
// 39.675 us; speedup vs baseline: 1.2272x; 1.2272x over previous
//
#include <hip/hip_runtime.h>
#include <math.h>

#define N 4096
#define D 128
#define NROW 16               // rows per block
#define NBLKS 256             // one 16-row panel per block
#define BIGV 1e30f
#define E1C  2.718281828459045f     // e^1  (mode-1 pos post-scale)
#define EM5C 0.006737946999085467f  // e^-5 (mode-1 neg post-scale)

typedef __bf16 bf16x8 __attribute__((ext_vector_type(8)));
typedef float  f32x4  __attribute__((ext_vector_type(4)));
typedef __attribute__((address_space(3))) unsigned lds_u32;
typedef const __attribute__((address_space(1))) unsigned glb_u32;

__device__ __forceinline__ void stg(float* p, float v) {
  __hip_atomic_store(p, v, __ATOMIC_RELAXED, __HIP_MEMORY_SCOPE_AGENT);
}
__device__ __forceinline__ float ldg1(const float* p) {
  return __hip_atomic_load((float*)p, __ATOMIC_RELAXED, __HIP_MEMORY_SCOPE_AGENT);
}

// split 8 f32 -> 8 bf16 hi + 8 bf16 lo (rne/rne; proven bit-exact path)
__device__ __forceinline__ void cvt8(float4 v0, float4 v1, int4& hp, int4& lp) {
  float vf[8] = {v0.x, v0.y, v0.z, v0.w, v1.x, v1.y, v1.z, v1.w};
  unsigned h[8], l[8];
#pragma unroll
  for (int i = 0; i < 8; ++i) {
    unsigned u = __float_as_uint(vf[i]);
    unsigned hr = (u + 0x7FFFu + ((u >> 16) & 1u)) >> 16;
    float hv = __uint_as_float(hr << 16);
    unsigned ul = __float_as_uint(vf[i] - hv);
    l[i] = (ul + 0x7FFFu + ((ul >> 16) & 1u)) >> 16;
    h[i] = hr;
  }
  hp = make_int4((int)(h[0] | (h[1] << 16)), (int)(h[2] | (h[3] << 16)),
                 (int)(h[4] | (h[5] << 16)), (int)(h[6] | (h[7] << 16)));
  lp = make_int4((int)(l[0] | (l[1] << 16)), (int)(l[2] | (l[3] << 16)),
                 (int)(l[4] | (l[5] << 16)), (int)(l[6] | (l[7] << 16)));
}
__device__ __forceinline__ void cvt8hi(float4 v0, float4 v1, int4& hp) {
  float vf[8] = {v0.x, v0.y, v0.z, v0.w, v1.x, v1.y, v1.z, v1.w};
  unsigned h[8];
#pragma unroll
  for (int i = 0; i < 8; ++i) {
    unsigned u = __float_as_uint(vf[i]);
    h[i] = (u + 0x7FFFu + ((u >> 16) & 1u)) >> 16;
  }
  hp = make_int4((int)(h[0] | (h[1] << 16)), (int)(h[2] | (h[3] << 16)),
                 (int)(h[4] | (h[5] << 16)), (int)(h[6] | (h[7] << 16)));
}

// ---- convert kernel: x -> bf16-hi in MFMA-fragment-linear order ----
// unit = ((C>>4)*4 + (k16>>2))*64 + (k16&3)*16 + (C&15); 16B per unit.
// Also resets the done-counter (replaces a separate memset dispatch).
__global__ __launch_bounds__(256)
void k_conv(const float* __restrict__ x, ushort* __restrict__ xf, unsigned* done)
{
  if (blockIdx.x == 0 && threadIdx.x == 0)
    __hip_atomic_store(done, 0u, __ATOMIC_RELAXED, __HIP_MEMORY_SCOPE_AGENT);
  int gid = blockIdx.x * 256 + threadIdx.x;     // 65536 = 4096 C x 16 k16
  int C = gid >> 4, k16 = gid & 15;
  const float* ap = x + C * D + k16 * 8;
  float4 v0 = *(const float4*)ap, v1 = *(const float4*)(ap + 4);
  int4 hp;
  cvt8hi(v0, v1, hp);
  int unit = ((C >> 4) * 4 + (k16 >> 2)) * 64 + (k16 & 3) * 16 + (C & 15);
  *(int4*)((char*)xf + ((size_t)unit << 4)) = hp;
}

#define VMCNT(n) asm volatile("s_waitcnt vmcnt(" #n ")" ::: "memory")

// stage tile ct_ (4 KB: 4 kt x 64 lanes x 16B) into wave-private buffer b_
#define STAGE(b_, ct_) do {                                                        \
    const char* gsrc_ = (const char*)xf + ((size_t)(ct_) << 12) + (l << 4);        \
    char* ldst_ = bbase + ((b_) << 12);                                            \
    _Pragma("unroll")                                                              \
    for (int kt_ = 0; kt_ < 4; ++kt_)                                              \
      __builtin_amdgcn_global_load_lds((glb_u32*)(gsrc_ + (kt_ << 10)),            \
                                       (lds_u32*)(ldst_ + (kt_ << 10)), 16, 0, 0); \
  } while (0)

__global__ __launch_bounds__(1024, 1)
void k_main(const float* __restrict__ x, const int* __restrict__ tgt,
            const float* __restrict__ marg, const float* __restrict__ wgt,
            const int* __restrict__ hm, float* __restrict__ out,
            const ushort* __restrict__ xf, float* __restrict__ lpart,
            unsigned* __restrict__ done)
{
  __shared__ __bf16 Bbuf[16][2][2048];          // 16 waves x 2 x 4 KB = 128 KB
  __shared__ float redA[16][16], redB[16][16], redC[16][16];
  __shared__ float finMn[16], finMx[16], lsRow[16];
  __shared__ float lsum[4];
  __shared__ unsigned lastf;

  const int tid = threadIdx.x;
  const int bid = blockIdx.x;
  const int w = tid >> 6, l = tid & 63;     // 16 waves; wave w owns cols [w*256, w*256+256)
  const int c = l & 15, g = l >> 4;
  const int i0 = bid * NROW;
  char* bbase = (char*)&Bbuf[w][0][0];

  const int trg = tgt[i0 + c];              // this lane's row target (scalar)

  // ---- A fragments (16 rows, hi+lo) in registers: row i0+c, k = kt*32 + g*8 ----
  bf16x8 Ah[4], Al[4];
#pragma unroll
  for (int kt = 0; kt < 4; ++kt) {
    const float* ap = x + (i0 + c) * D + kt * 32 + g * 8;
    float4 v0 = *(const float4*)ap, v1 = *(const float4*)(ap + 4);
    int4 hp, lp;
    cvt8(v0, v1, hp, lp);
    Ah[kt] = *(bf16x8*)&hp;
    Al[kt] = *(bf16x8*)&lp;
  }

  f32x4 acc[16];
#pragma unroll
  for (int ci = 0; ci < 16; ++ci) acc[ci] = f32x4{0.f, 0.f, 0.f, 0.f};

  // ---- K-loop: LDS dbuf + counted vmcnt(5) (4 stage + 1 tgt-int4 per tile).
  //      TRANSPOSED attribution: acc[ci][jj] = sim[row i0+c][col ct*16+g*4+jj]
  //      (operand swap mfma(B,A) is free; row state is scalar per lane).
  float mn = BIGV, mx = -BIGV;
  STAGE(0, (w << 4));
  int4 tq_next = *(const int4*)&tgt[(w << 4) * 16 + (g << 2)];
#pragma unroll
  for (int ci = 0; ci < 16; ++ci) {
    const int4 tq = tq_next;
    if (ci + 1 < 16) {
      STAGE((ci + 1) & 1, (w << 4) + ci + 1);
      tq_next = *(const int4*)&tgt[((w << 4) + ci + 1) * 16 + (g << 2)];
      VMCNT(5);                 // drains tile ci's 4 stages + tq; next 5 in flight
    } else {
      VMCNT(0);
    }
    const int ct = (w << 4) + ci;
    if (ct == bid) {
      // diagonal tile: exact 3-product from A registers (order-symmetric set)
#pragma unroll
      for (int kt = 0; kt < 4; ++kt) {
        acc[ci] = __builtin_amdgcn_mfma_f32_16x16x32_bf16(Ah[kt], Ah[kt], acc[ci], 0, 0, 0);
        acc[ci] = __builtin_amdgcn_mfma_f32_16x16x32_bf16(Ah[kt], Al[kt], acc[ci], 0, 0, 0);
        acc[ci] = __builtin_amdgcn_mfma_f32_16x16x32_bf16(Al[kt], Ah[kt], acc[ci], 0, 0, 0);
      }
    } else {
      const char* bp = bbase + ((ci & 1) << 12) + (l << 4);
#pragma unroll
      for (int kt = 0; kt < 4; ++kt) {
        bf16x8 Bh = *(const bf16x8*)(bp + (kt << 10));
        acc[ci] = __builtin_amdgcn_mfma_f32_16x16x32_bf16(Bh, Ah[kt], acc[ci], 0, 0, 0);
        acc[ci] = __builtin_amdgcn_mfma_f32_16x16x32_bf16(Bh, Al[kt], acc[ci], 0, 0, 0);
      }
    }
    // fused pass-1 scan (scalar row state)
    const int tca[4] = {tq.x, tq.y, tq.z, tq.w};
#pragma unroll
    for (int jj = 0; jj < 4; ++jj) {
      float s = acc[ci][jj];
      if (tca[jj] == trg) { if (s < 1.0f) mn = fminf(mn, s); }
      else                  mx = fmaxf(mx, s);
    }
  }

  // ---- reduce min/max: across the 4 g-groups, then across waves ----
  mn = fminf(mn, __shfl_xor(mn, 16, 64));
  mn = fminf(mn, __shfl_xor(mn, 32, 64));
  mx = fmaxf(mx, __shfl_xor(mx, 16, 64));
  mx = fmaxf(mx, __shfl_xor(mx, 32, 64));
  if (l < 16) { redA[w][c] = mn; redB[w][c] = mx; }
  __syncthreads();
  if (tid < 16) {
    float a0 = BIGV, b0 = -BIGV;
#pragma unroll
    for (int w16 = 0; w16 < 16; ++w16) {
      a0 = fminf(a0, redA[w16][tid]);
      b0 = fmaxf(b0, redB[w16][tid]);
    }
    finMn[tid] = a0; finMx[tid] = b0;
  }
  __syncthreads();

  // ---- mining epilogue: merged thresholds + factored exp (scalar row state) ----
  const int mode = hm[0];
  float thrP, thrN, wp, wn;
  {
    float mg = marg[i0 + c], wt = wgt[i0 + c];
    if (mode == 1) {
      thrP = fminf(1.0f, finMx[c] + mg);   // same && s<1 && s<mxn+mg
      thrN = finMn[c] - mg;                // diff && s>mnp-mg
      wp = -2.f * wt; wn = 10.f * wt;
    } else {
      thrP = 1.0f; thrN = -BIGV;
      wp = -2.f; wn = 10.f;
    }
  }
  float ps = 0.f, ns = 0.f, cnt = 0.f;     // cnt = ap + 4096*an (exact <= 2^24)
#pragma unroll
  for (int ci = 0; ci < 16; ++ci) {
    const int ct = (w << 4) + ci;
    int4 tq = *(const int4*)&tgt[ct * 16 + (g << 2)];   // L1-hot
    const int tca[4] = {tq.x, tq.y, tq.z, tq.w};
#pragma unroll
    for (int jj = 0; jj < 4; ++jj) {
      float s = acc[ci][jj];
      if (tca[jj] == trg) {
        if (s < thrP) { ps += __expf(wp * s); cnt += 1.f; }
      } else {
        if (s > thrN) { ns += __expf(wn * s); cnt += 4096.f; }
      }
    }
  }
  ps  += __shfl_xor(ps, 16, 64);  ps  += __shfl_xor(ps, 32, 64);
  ns  += __shfl_xor(ns, 16, 64);  ns  += __shfl_xor(ns, 32, 64);
  cnt += __shfl_xor(cnt, 16, 64); cnt += __shfl_xor(cnt, 32, 64);
  if (l < 16) { redA[w][c] = ps; redB[w][c] = ns; redC[w][c] = cnt; }
  __syncthreads();

  if (tid < 16) {
    float tps = 0.f, tns = 0.f, tcnt = 0.f;
#pragma unroll
    for (int w16 = 0; w16 < 16; ++w16) {
      tps += redA[w16][tid]; tns += redB[w16][tid]; tcnt += redC[w16][tid];
    }
    float an = floorf(tcnt * (1.0f / 4096.0f));
    float ap = tcnt - an * 4096.0f;
    float mg = marg[i0 + tid];
    float sP = (mode == 1) ? E1C  : __expf(1.f + 2.f * mg);
    float sN = (mode == 1) ? EM5C : __expf(-5.f + 10.f * mg);
    float loss_i = log1pf(tps * sP) + 0.2f * log1pf(tns * sN);
    if (mode == 1 && (ap + an) < 1.0f) { loss_i = 0.f; ap = 0.f; an = 0.f; }
    out[1 + i0 + tid]     = ap;
    out[1 + N + i0 + tid] = an;
    lsRow[tid] = loss_i;
  }
  __syncthreads();
  if (tid == 0) {
    float lb = 0.f;
#pragma unroll
    for (int r = 0; r < 16; ++r) lb += lsRow[r];
    stg(&lpart[bid], lb);
    asm volatile("s_waitcnt vmcnt(0)" ::: "memory");
    unsigned o = __hip_atomic_fetch_add(done, 1u, __ATOMIC_ACQ_REL, __HIP_MEMORY_SCOPE_AGENT);
    lastf = (o == (unsigned)(NBLKS - 1)) ? 1u : 0u;
  }
  __syncthreads();

  // ---- last block deterministically sums the 256 loss partials ----
  if (lastf) {
    float v = (tid < NBLKS) ? ldg1(&lpart[tid]) : 0.f;
#pragma unroll
    for (int msk = 32; msk; msk >>= 1) v += __shfl_down(v, msk, 64);
    if (tid < NBLKS && (tid & 63) == 0) lsum[tid >> 6] = v;
    __syncthreads();
    if (tid == 0) {
      float s = 0.f;
#pragma unroll
      for (int k2 = 0; k2 < 4; ++k2) s += lsum[k2];
      out[0] = s / (float)N;
    }
  }
}

extern "C" void kernel_launch(void* const* d_in, const int* in_sizes, int n_in,
                              void* d_out, int out_size, void* d_ws, size_t ws_size,
                              hipStream_t stream)
{
  (void)in_sizes; (void)n_in; (void)out_size; (void)ws_size;
  const float* x    = (const float*)d_in[0];
  const int*   tgt  = (const int*)d_in[1];
  const float* marg = (const float*)d_in[2];
  const float* wgt  = (const float*)d_in[3];
  const int*   hm   = (const int*)d_in[4];
  float* out = (float*)d_out;

  ushort*   xf    = (ushort*)d_ws;                          // 1 MB fragment-linear bf16-hi
  float*    lpart = (float*)((char*)d_ws + (1 << 20));      // 256 loss partials
  unsigned* done  = (unsigned*)(lpart + NBLKS);             // 1 counter

  k_conv<<<256, 256, 0, stream>>>(x, xf, done);
  k_main<<<NBLKS, 1024, 0, stream>>>(x, tgt, marg, wgt, hm, out, xf, lpart, done);
}

// Round 23
// 38.897 us; speedup vs baseline: 1.2518x; 1.0200x over previous
//
#include <hip/hip_runtime.h>
#include <math.h>

#define N 4096
#define D 128
#define NROW 16               // rows per block
#define NBLKS 256             // one 16-row panel per block
#define BIGV 1e30f
#define E1C  2.718281828459045f     // e^1  (mode-1 pos post-scale)
#define EM5C 0.006737946999085467f  // e^-5 (mode-1 neg post-scale)

typedef __bf16 bf16x8 __attribute__((ext_vector_type(8)));
typedef float  f32x4  __attribute__((ext_vector_type(4)));
typedef __attribute__((address_space(3))) unsigned lds_u32;
typedef const __attribute__((address_space(1))) unsigned glb_u32;

__device__ __forceinline__ void stg(float* p, float v) {
  __hip_atomic_store(p, v, __ATOMIC_RELAXED, __HIP_MEMORY_SCOPE_AGENT);
}
__device__ __forceinline__ float ldg1(const float* p) {
  return __hip_atomic_load((float*)p, __ATOMIC_RELAXED, __HIP_MEMORY_SCOPE_AGENT);
}

// split 8 f32 -> 8 bf16 hi + 8 bf16 lo (rne/rne; proven bit-exact path)
__device__ __forceinline__ void cvt8(float4 v0, float4 v1, int4& hp, int4& lp) {
  float vf[8] = {v0.x, v0.y, v0.z, v0.w, v1.x, v1.y, v1.z, v1.w};
  unsigned h[8], l[8];
#pragma unroll
  for (int i = 0; i < 8; ++i) {
    unsigned u = __float_as_uint(vf[i]);
    unsigned hr = (u + 0x7FFFu + ((u >> 16) & 1u)) >> 16;
    float hv = __uint_as_float(hr << 16);
    unsigned ul = __float_as_uint(vf[i] - hv);
    l[i] = (ul + 0x7FFFu + ((ul >> 16) & 1u)) >> 16;
    h[i] = hr;
  }
  hp = make_int4((int)(h[0] | (h[1] << 16)), (int)(h[2] | (h[3] << 16)),
                 (int)(h[4] | (h[5] << 16)), (int)(h[6] | (h[7] << 16)));
  lp = make_int4((int)(l[0] | (l[1] << 16)), (int)(l[2] | (l[3] << 16)),
                 (int)(l[4] | (l[5] << 16)), (int)(l[6] | (l[7] << 16)));
}
__device__ __forceinline__ void cvt8hi(float4 v0, float4 v1, int4& hp) {
  float vf[8] = {v0.x, v0.y, v0.z, v0.w, v1.x, v1.y, v1.z, v1.w};
  unsigned h[8];
#pragma unroll
  for (int i = 0; i < 8; ++i) {
    unsigned u = __float_as_uint(vf[i]);
    h[i] = (u + 0x7FFFu + ((u >> 16) & 1u)) >> 16;
  }
  hp = make_int4((int)(h[0] | (h[1] << 16)), (int)(h[2] | (h[3] << 16)),
                 (int)(h[4] | (h[5] << 16)), (int)(h[6] | (h[7] << 16)));
}

// ---- convert kernel: x -> bf16-hi in MFMA-fragment-linear order ----
// unit = ((C>>4)*4 + (k16>>2))*64 + (k16&3)*16 + (C&15); 16B per unit.
// Also resets the done-counter (replaces a separate memset dispatch).
__global__ __launch_bounds__(256)
void k_conv(const float* __restrict__ x, ushort* __restrict__ xf, unsigned* done)
{
  if (blockIdx.x == 0 && threadIdx.x == 0)
    __hip_atomic_store(done, 0u, __ATOMIC_RELAXED, __HIP_MEMORY_SCOPE_AGENT);
  int gid = blockIdx.x * 256 + threadIdx.x;     // 65536 = 4096 C x 16 k16
  int C = gid >> 4, k16 = gid & 15;
  const float* ap = x + C * D + k16 * 8;
  float4 v0 = *(const float4*)ap, v1 = *(const float4*)(ap + 4);
  int4 hp;
  cvt8hi(v0, v1, hp);
  int unit = ((C >> 4) * 4 + (k16 >> 2)) * 64 + (k16 & 3) * 16 + (C & 15);
  *(int4*)((char*)xf + ((size_t)unit << 4)) = hp;
}

#define VMCNT(n) asm volatile("s_waitcnt vmcnt(" #n ")" ::: "memory")

// stage tile ct_ (4 KB: 4 kt x 64 lanes x 16B) into wave-private buffer b_
#define STAGE(b_, ct_) do {                                                        \
    const char* gsrc_ = (const char*)xf + ((size_t)(ct_) << 12) + (l << 4);        \
    char* ldst_ = bbase + ((b_) << 12);                                            \
    _Pragma("unroll")                                                              \
    for (int kt_ = 0; kt_ < 4; ++kt_)                                              \
      __builtin_amdgcn_global_load_lds((glb_u32*)(gsrc_ + (kt_ << 10)),            \
                                       (lds_u32*)(ldst_ + (kt_ << 10)), 16, 0, 0); \
  } while (0)

__global__ __launch_bounds__(1024, 1)
void k_main(const float* __restrict__ x, const int* __restrict__ tgt,
            const float* __restrict__ marg, const float* __restrict__ wgt,
            const int* __restrict__ hm, float* __restrict__ out,
            const ushort* __restrict__ xf, float* __restrict__ lpart,
            unsigned* __restrict__ done)
{
  __shared__ __bf16 Bbuf[16][2][2048];          // 16 waves x 2 x 4 KB = 128 KB
  __shared__ int   tgL[4096];                   // all targets, block-resident (16 KB)
  __shared__ float redA[16][16], redB[16][16], redC[16][16];
  __shared__ float finMn[16], finMx[16], lsRow[16];
  __shared__ float lsum[4];
  __shared__ unsigned lastf;

  const int tid = threadIdx.x;
  const int bid = blockIdx.x;
  const int w = tid >> 6, l = tid & 63;     // 16 waves; wave w owns cols [w*256, w*256+256)
  const int c = l & 15, g = l >> 4;
  const int i0 = bid * NROW;
  char* bbase = (char*)&Bbuf[w][0][0];

  // ---- stage all 4096 targets into LDS (coalesced, once) ----
#pragma unroll
  for (int r = 0; r < 4; ++r) tgL[tid + r * 1024] = tgt[tid + r * 1024];

  // ---- A fragments (16 rows, hi+lo) in registers: row i0+c, k = kt*32 + g*8 ----
  bf16x8 Ah[4], Al[4];
#pragma unroll
  for (int kt = 0; kt < 4; ++kt) {
    const float* ap = x + (i0 + c) * D + kt * 32 + g * 8;
    float4 v0 = *(const float4*)ap, v1 = *(const float4*)(ap + 4);
    int4 hp, lp;
    cvt8(v0, v1, hp, lp);
    Ah[kt] = *(bf16x8*)&hp;
    Al[kt] = *(bf16x8*)&lp;
  }

  f32x4 acc[16];
#pragma unroll
  for (int ci = 0; ci < 16; ++ci) acc[ci] = f32x4{0.f, 0.f, 0.f, 0.f};

  __syncthreads();                          // tgL ready
  const int trg = tgL[i0 + c];              // this lane's row target (scalar)

  // ---- K-loop: LDS dbuf + pure-STAGE vmcnt(4); targets from LDS.
  //      TRANSPOSED attribution: acc[ci][jj] = sim[row i0+c][col ct*16+g*4+jj].
  float mn = BIGV, mx = -BIGV;
  STAGE(0, (w << 4));
#pragma unroll
  for (int ci = 0; ci < 16; ++ci) {
    if (ci + 1 < 16) {
      STAGE((ci + 1) & 1, (w << 4) + ci + 1);
      VMCNT(4);                 // tile ci's 4 stages drained; next 4 in flight
    } else {
      VMCNT(0);
    }
    const int ct = (w << 4) + ci;
    __builtin_amdgcn_s_setprio(1);
    if (ct == bid) {
      // diagonal tile: exact 3-product from A registers (order-symmetric set)
#pragma unroll
      for (int kt = 0; kt < 4; ++kt) {
        acc[ci] = __builtin_amdgcn_mfma_f32_16x16x32_bf16(Ah[kt], Ah[kt], acc[ci], 0, 0, 0);
        acc[ci] = __builtin_amdgcn_mfma_f32_16x16x32_bf16(Ah[kt], Al[kt], acc[ci], 0, 0, 0);
        acc[ci] = __builtin_amdgcn_mfma_f32_16x16x32_bf16(Al[kt], Ah[kt], acc[ci], 0, 0, 0);
      }
    } else {
      const char* bp = bbase + ((ci & 1) << 12) + (l << 4);
#pragma unroll
      for (int kt = 0; kt < 4; ++kt) {
        bf16x8 Bh = *(const bf16x8*)(bp + (kt << 10));
        acc[ci] = __builtin_amdgcn_mfma_f32_16x16x32_bf16(Bh, Ah[kt], acc[ci], 0, 0, 0);
        acc[ci] = __builtin_amdgcn_mfma_f32_16x16x32_bf16(Bh, Al[kt], acc[ci], 0, 0, 0);
      }
    }
    __builtin_amdgcn_s_setprio(0);
    // fused pass-1 scan (scalar row state; targets broadcast from LDS)
    int4 tq = *(const int4*)&tgL[ct * 16 + (g << 2)];
    const int tca[4] = {tq.x, tq.y, tq.z, tq.w};
#pragma unroll
    for (int jj = 0; jj < 4; ++jj) {
      float s = acc[ci][jj];
      if (tca[jj] == trg) { if (s < 1.0f) mn = fminf(mn, s); }
      else                  mx = fmaxf(mx, s);
    }
  }

  // ---- reduce min/max: across the 4 g-groups, then across waves ----
  mn = fminf(mn, __shfl_xor(mn, 16, 64));
  mn = fminf(mn, __shfl_xor(mn, 32, 64));
  mx = fmaxf(mx, __shfl_xor(mx, 16, 64));
  mx = fmaxf(mx, __shfl_xor(mx, 32, 64));
  if (l < 16) { redA[w][c] = mn; redB[w][c] = mx; }
  __syncthreads();
  if (tid < 16) {
    float a0 = BIGV, b0 = -BIGV;
#pragma unroll
    for (int w16 = 0; w16 < 16; ++w16) {
      a0 = fminf(a0, redA[w16][tid]);
      b0 = fmaxf(b0, redB[w16][tid]);
    }
    finMn[tid] = a0; finMx[tid] = b0;
  }
  __syncthreads();

  // ---- mining epilogue: merged thresholds + factored exp (scalar row state) ----
  const int mode = hm[0];
  float thrP, thrN, wp, wn;
  {
    float mg = marg[i0 + c], wt = wgt[i0 + c];
    if (mode == 1) {
      thrP = fminf(1.0f, finMx[c] + mg);   // same && s<1 && s<mxn+mg
      thrN = finMn[c] - mg;                // diff && s>mnp-mg
      wp = -2.f * wt; wn = 10.f * wt;
    } else {
      thrP = 1.0f; thrN = -BIGV;
      wp = -2.f; wn = 10.f;
    }
  }
  float ps = 0.f, ns = 0.f, cnt = 0.f;     // cnt = ap + 4096*an (exact <= 2^24)
#pragma unroll
  for (int ci = 0; ci < 16; ++ci) {
    const int ct = (w << 4) + ci;
    int4 tq = *(const int4*)&tgL[ct * 16 + (g << 2)];
    const int tca[4] = {tq.x, tq.y, tq.z, tq.w};
#pragma unroll
    for (int jj = 0; jj < 4; ++jj) {
      float s = acc[ci][jj];
      if (tca[jj] == trg) {
        if (s < thrP) { ps += __expf(wp * s); cnt += 1.f; }
      } else {
        if (s > thrN) { ns += __expf(wn * s); cnt += 4096.f; }
      }
    }
  }
  ps  += __shfl_xor(ps, 16, 64);  ps  += __shfl_xor(ps, 32, 64);
  ns  += __shfl_xor(ns, 16, 64);  ns  += __shfl_xor(ns, 32, 64);
  cnt += __shfl_xor(cnt, 16, 64); cnt += __shfl_xor(cnt, 32, 64);
  if (l < 16) { redA[w][c] = ps; redB[w][c] = ns; redC[w][c] = cnt; }
  __syncthreads();

  if (tid < 16) {
    float tps = 0.f, tns = 0.f, tcnt = 0.f;
#pragma unroll
    for (int w16 = 0; w16 < 16; ++w16) {
      tps += redA[w16][tid]; tns += redB[w16][tid]; tcnt += redC[w16][tid];
    }
    float an = floorf(tcnt * (1.0f / 4096.0f));
    float ap = tcnt - an * 4096.0f;
    float mg = marg[i0 + tid];
    float sP = (mode == 1) ? E1C  : __expf(1.f + 2.f * mg);
    float sN = (mode == 1) ? EM5C : __expf(-5.f + 10.f * mg);
    float loss_i = log1pf(tps * sP) + 0.2f * log1pf(tns * sN);
    if (mode == 1 && (ap + an) < 1.0f) { loss_i = 0.f; ap = 0.f; an = 0.f; }
    out[1 + i0 + tid]     = ap;
    out[1 + N + i0 + tid] = an;
    lsRow[tid] = loss_i;
  }
  __syncthreads();
  if (tid == 0) {
    float lb = 0.f;
#pragma unroll
    for (int r = 0; r < 16; ++r) lb += lsRow[r];
    stg(&lpart[bid], lb);
    asm volatile("s_waitcnt vmcnt(0)" ::: "memory");
    unsigned o = __hip_atomic_fetch_add(done, 1u, __ATOMIC_ACQ_REL, __HIP_MEMORY_SCOPE_AGENT);
    lastf = (o == (unsigned)(NBLKS - 1)) ? 1u : 0u;
  }
  __syncthreads();

  // ---- last block deterministically sums the 256 loss partials ----
  if (lastf) {
    float v = (tid < NBLKS) ? ldg1(&lpart[tid]) : 0.f;
#pragma unroll
    for (int msk = 32; msk; msk >>= 1) v += __shfl_down(v, msk, 64);
    if (tid < NBLKS && (tid & 63) == 0) lsum[tid >> 6] = v;
    __syncthreads();
    if (tid == 0) {
      float s = 0.f;
#pragma unroll
      for (int k2 = 0; k2 < 4; ++k2) s += lsum[k2];
      out[0] = s / (float)N;
    }
  }
}

extern "C" void kernel_launch(void* const* d_in, const int* in_sizes, int n_in,
                              void* d_out, int out_size, void* d_ws, size_t ws_size,
                              hipStream_t stream)
{
  (void)in_sizes; (void)n_in; (void)out_size; (void)ws_size;
  const float* x    = (const float*)d_in[0];
  const int*   tgt  = (const int*)d_in[1];
  const float* marg = (const float*)d_in[2];
  const float* wgt  = (const float*)d_in[3];
  const int*   hm   = (const int*)d_in[4];
  float* out = (float*)d_out;

  ushort*   xf    = (ushort*)d_ws;                          // 1 MB fragment-linear bf16-hi
  float*    lpart = (float*)((char*)d_ws + (1 << 20));      // 256 loss partials
  unsigned* done  = (unsigned*)(lpart + NBLKS);             // 1 counter

  k_conv<<<256, 256, 0, stream>>>(x, xf, done);
  k_main<<<NBLKS, 1024, 0, stream>>>(x, tgt, marg, wgt, hm, out, xf, lpart, done);
}

// Round 24
// 38.150 us; speedup vs baseline: 1.2762x; 1.0196x over previous
//
#include <hip/hip_runtime.h>
#include <math.h>

#define N 4096
#define D 128
#define NROW 16               // rows per block
#define NBLKS 256             // one 16-row panel per block
#define BIGV 1e30f
#define E1C  2.718281828459045f     // e^1  (mode-1 pos post-scale)
#define EM5C 0.006737946999085467f  // e^-5 (mode-1 neg post-scale)

typedef __bf16 bf16x8 __attribute__((ext_vector_type(8)));
typedef float  f32x4  __attribute__((ext_vector_type(4)));
typedef __attribute__((address_space(3))) unsigned lds_u32;
typedef const __attribute__((address_space(1))) unsigned glb_u32;

__device__ __forceinline__ void stg(float* p, float v) {
  __hip_atomic_store(p, v, __ATOMIC_RELAXED, __HIP_MEMORY_SCOPE_AGENT);
}
__device__ __forceinline__ float ldg1(const float* p) {
  return __hip_atomic_load((float*)p, __ATOMIC_RELAXED, __HIP_MEMORY_SCOPE_AGENT);
}

// split 8 f32 -> 8 bf16 hi + 8 bf16 lo (rne/rne; proven bit-exact path)
__device__ __forceinline__ void cvt8(float4 v0, float4 v1, int4& hp, int4& lp) {
  float vf[8] = {v0.x, v0.y, v0.z, v0.w, v1.x, v1.y, v1.z, v1.w};
  unsigned h[8], l[8];
#pragma unroll
  for (int i = 0; i < 8; ++i) {
    unsigned u = __float_as_uint(vf[i]);
    unsigned hr = (u + 0x7FFFu + ((u >> 16) & 1u)) >> 16;
    float hv = __uint_as_float(hr << 16);
    unsigned ul = __float_as_uint(vf[i] - hv);
    l[i] = (ul + 0x7FFFu + ((ul >> 16) & 1u)) >> 16;
    h[i] = hr;
  }
  hp = make_int4((int)(h[0] | (h[1] << 16)), (int)(h[2] | (h[3] << 16)),
                 (int)(h[4] | (h[5] << 16)), (int)(h[6] | (h[7] << 16)));
  lp = make_int4((int)(l[0] | (l[1] << 16)), (int)(l[2] | (l[3] << 16)),
                 (int)(l[4] | (l[5] << 16)), (int)(l[6] | (l[7] << 16)));
}
__device__ __forceinline__ void cvt8hi(float4 v0, float4 v1, int4& hp) {
  float vf[8] = {v0.x, v0.y, v0.z, v0.w, v1.x, v1.y, v1.z, v1.w};
  unsigned h[8];
#pragma unroll
  for (int i = 0; i < 8; ++i) {
    unsigned u = __float_as_uint(vf[i]);
    h[i] = (u + 0x7FFFu + ((u >> 16) & 1u)) >> 16;
  }
  hp = make_int4((int)(h[0] | (h[1] << 16)), (int)(h[2] | (h[3] << 16)),
                 (int)(h[4] | (h[5] << 16)), (int)(h[6] | (h[7] << 16)));
}

// ---- convert kernel: x -> bf16-hi in MFMA-fragment-linear order ----
// unit = ((C>>4)*4 + (k16>>2))*64 + (k16&3)*16 + (C&15); 16B per unit.
// Also resets the done-counter (replaces a separate memset dispatch).
__global__ __launch_bounds__(256)
void k_conv(const float* __restrict__ x, ushort* __restrict__ xf, unsigned* done)
{
  if (blockIdx.x == 0 && threadIdx.x == 0)
    __hip_atomic_store(done, 0u, __ATOMIC_RELAXED, __HIP_MEMORY_SCOPE_AGENT);
  int gid = blockIdx.x * 256 + threadIdx.x;     // 65536 = 4096 C x 16 k16
  int C = gid >> 4, k16 = gid & 15;
  const float* ap = x + C * D + k16 * 8;
  float4 v0 = *(const float4*)ap, v1 = *(const float4*)(ap + 4);
  int4 hp;
  cvt8hi(v0, v1, hp);
  int unit = ((C >> 4) * 4 + (k16 >> 2)) * 64 + (k16 & 3) * 16 + (C & 15);
  *(int4*)((char*)xf + ((size_t)unit << 4)) = hp;
}

#define VMCNT(n) asm volatile("s_waitcnt vmcnt(" #n ")" ::: "memory")

// stage tile ct_ (4 KB: 4 kt x 64 lanes x 16B) into wave-private buffer b_
#define STAGE(b_, ct_) do {                                                        \
    const char* gsrc_ = (const char*)xf + ((size_t)(ct_) << 12) + (l << 4);        \
    char* ldst_ = bbase + ((b_) << 12);                                            \
    _Pragma("unroll")                                                              \
    for (int kt_ = 0; kt_ < 4; ++kt_)                                              \
      __builtin_amdgcn_global_load_lds((glb_u32*)(gsrc_ + (kt_ << 10)),            \
                                       (lds_u32*)(ldst_ + (kt_ << 10)), 16, 0, 0); \
  } while (0)

__global__ __launch_bounds__(1024, 1)
void k_main(const float* __restrict__ x, const int* __restrict__ tgt,
            const float* __restrict__ marg, const float* __restrict__ wgt,
            const int* __restrict__ hm, float* __restrict__ out,
            const ushort* __restrict__ xf, float* __restrict__ lpart,
            unsigned* __restrict__ done)
{
  __shared__ __bf16 Bbuf[16][2][2048];          // 16 waves x 2 x 4 KB = 128 KB
  __shared__ int   tgL[4096];                   // all targets, block-resident (16 KB)
  __shared__ float redA[16][16], redB[16][16], redC[16][16];
  __shared__ float finMn[16], finMx[16], lsRow[16];
  __shared__ float lsum[4];
  __shared__ unsigned lastf;

  const int tid = threadIdx.x;
  const int bid = blockIdx.x;
  const int w = tid >> 6, l = tid & 63;     // 16 waves; wave w owns cols [w*256, w*256+256)
  const int c = l & 15, g = l >> 4;
  const int i0 = bid * NROW;
  char* bbase = (char*)&Bbuf[w][0][0];

  // ---- stage all 4096 targets into LDS (coalesced, once) ----
#pragma unroll
  for (int r = 0; r < 4; ++r) tgL[tid + r * 1024] = tgt[tid + r * 1024];

  // ---- A fragments (16 rows, hi+lo) in registers: row i0+c, k = kt*32 + g*8 ----
  bf16x8 Ah[4], Al[4];
#pragma unroll
  for (int kt = 0; kt < 4; ++kt) {
    const float* ap = x + (i0 + c) * D + kt * 32 + g * 8;
    float4 v0 = *(const float4*)ap, v1 = *(const float4*)(ap + 4);
    int4 hp, lp;
    cvt8(v0, v1, hp, lp);
    Ah[kt] = *(bf16x8*)&hp;
    Al[kt] = *(bf16x8*)&lp;
  }

  f32x4 acc[16];
#pragma unroll
  for (int ci = 0; ci < 16; ++ci) acc[ci] = f32x4{0.f, 0.f, 0.f, 0.f};

  __syncthreads();                          // tgL ready
  const int trg = tgL[i0 + c];              // this lane's row target (scalar)

  // ---- K-loop: LDS dbuf + pure-STAGE vmcnt(4); targets from LDS.
  //      TRANSPOSED attribution: acc[ci][jj] = sim[row i0+c][col ct*16+g*4+jj].
  //      Off-diag: 1-product hiB*hiA (|err| ~2x the proven 2-product; margin 2.5x).
  float mn = BIGV, mx = -BIGV;
  STAGE(0, (w << 4));
#pragma unroll
  for (int ci = 0; ci < 16; ++ci) {
    if (ci + 1 < 16) {
      STAGE((ci + 1) & 1, (w << 4) + ci + 1);
      VMCNT(4);                 // tile ci's 4 stages drained; next 4 in flight
    } else {
      VMCNT(0);
    }
    const int ct = (w << 4) + ci;
    __builtin_amdgcn_s_setprio(1);
    if (ct == bid) {
      // diagonal tile: exact 3-product from A registers (self-sim path unchanged)
#pragma unroll
      for (int kt = 0; kt < 4; ++kt) {
        acc[ci] = __builtin_amdgcn_mfma_f32_16x16x32_bf16(Ah[kt], Ah[kt], acc[ci], 0, 0, 0);
        acc[ci] = __builtin_amdgcn_mfma_f32_16x16x32_bf16(Ah[kt], Al[kt], acc[ci], 0, 0, 0);
        acc[ci] = __builtin_amdgcn_mfma_f32_16x16x32_bf16(Al[kt], Ah[kt], acc[ci], 0, 0, 0);
      }
    } else {
      const char* bp = bbase + ((ci & 1) << 12) + (l << 4);
#pragma unroll
      for (int kt = 0; kt < 4; ++kt) {
        bf16x8 Bh = *(const bf16x8*)(bp + (kt << 10));
        acc[ci] = __builtin_amdgcn_mfma_f32_16x16x32_bf16(Bh, Ah[kt], acc[ci], 0, 0, 0);
      }
    }
    __builtin_amdgcn_s_setprio(0);
    // fused pass-1 scan (scalar row state; targets broadcast from LDS)
    int4 tq = *(const int4*)&tgL[ct * 16 + (g << 2)];
    const int tca[4] = {tq.x, tq.y, tq.z, tq.w};
#pragma unroll
    for (int jj = 0; jj < 4; ++jj) {
      float s = acc[ci][jj];
      if (tca[jj] == trg) { if (s < 1.0f) mn = fminf(mn, s); }
      else                  mx = fmaxf(mx, s);
    }
  }

  // ---- reduce min/max: across the 4 g-groups, then across waves ----
  mn = fminf(mn, __shfl_xor(mn, 16, 64));
  mn = fminf(mn, __shfl_xor(mn, 32, 64));
  mx = fmaxf(mx, __shfl_xor(mx, 16, 64));
  mx = fmaxf(mx, __shfl_xor(mx, 32, 64));
  if (l < 16) { redA[w][c] = mn; redB[w][c] = mx; }
  __syncthreads();
  if (tid < 16) {
    float a0 = BIGV, b0 = -BIGV;
#pragma unroll
    for (int w16 = 0; w16 < 16; ++w16) {
      a0 = fminf(a0, redA[w16][tid]);
      b0 = fmaxf(b0, redB[w16][tid]);
    }
    finMn[tid] = a0; finMx[tid] = b0;
  }
  __syncthreads();

  // ---- mining epilogue: merged thresholds + factored exp (scalar row state) ----
  const int mode = hm[0];
  float thrP, thrN, wp, wn;
  {
    float mg = marg[i0 + c], wt = wgt[i0 + c];
    if (mode == 1) {
      thrP = fminf(1.0f, finMx[c] + mg);   // same && s<1 && s<mxn+mg
      thrN = finMn[c] - mg;                // diff && s>mnp-mg
      wp = -2.f * wt; wn = 10.f * wt;
    } else {
      thrP = 1.0f; thrN = -BIGV;
      wp = -2.f; wn = 10.f;
    }
  }
  float ps = 0.f, ns = 0.f, cnt = 0.f;     // cnt = ap + 4096*an (exact <= 2^24)
#pragma unroll
  for (int ci = 0; ci < 16; ++ci) {
    const int ct = (w << 4) + ci;
    int4 tq = *(const int4*)&tgL[ct * 16 + (g << 2)];
    const int tca[4] = {tq.x, tq.y, tq.z, tq.w};
#pragma unroll
    for (int jj = 0; jj < 4; ++jj) {
      float s = acc[ci][jj];
      if (tca[jj] == trg) {
        if (s < thrP) { ps += __expf(wp * s); cnt += 1.f; }
      } else {
        if (s > thrN) { ns += __expf(wn * s); cnt += 4096.f; }
      }
    }
  }
  ps  += __shfl_xor(ps, 16, 64);  ps  += __shfl_xor(ps, 32, 64);
  ns  += __shfl_xor(ns, 16, 64);  ns  += __shfl_xor(ns, 32, 64);
  cnt += __shfl_xor(cnt, 16, 64); cnt += __shfl_xor(cnt, 32, 64);
  if (l < 16) { redA[w][c] = ps; redB[w][c] = ns; redC[w][c] = cnt; }
  __syncthreads();

  if (tid < 16) {
    float tps = 0.f, tns = 0.f, tcnt = 0.f;
#pragma unroll
    for (int w16 = 0; w16 < 16; ++w16) {
      tps += redA[w16][tid]; tns += redB[w16][tid]; tcnt += redC[w16][tid];
    }
    float an = floorf(tcnt * (1.0f / 4096.0f));
    float ap = tcnt - an * 4096.0f;
    float mg = marg[i0 + tid];
    float sP = (mode == 1) ? E1C  : __expf(1.f + 2.f * mg);
    float sN = (mode == 1) ? EM5C : __expf(-5.f + 10.f * mg);
    float loss_i = log1pf(tps * sP) + 0.2f * log1pf(tns * sN);
    if (mode == 1 && (ap + an) < 1.0f) { loss_i = 0.f; ap = 0.f; an = 0.f; }
    out[1 + i0 + tid]     = ap;
    out[1 + N + i0 + tid] = an;
    lsRow[tid] = loss_i;
  }
  __syncthreads();
  if (tid == 0) {
    float lb = 0.f;
#pragma unroll
    for (int r = 0; r < 16; ++r) lb += lsRow[r];
    stg(&lpart[bid], lb);
    asm volatile("s_waitcnt vmcnt(0)" ::: "memory");
    unsigned o = __hip_atomic_fetch_add(done, 1u, __ATOMIC_ACQ_REL, __HIP_MEMORY_SCOPE_AGENT);
    lastf = (o == (unsigned)(NBLKS - 1)) ? 1u : 0u;
  }
  __syncthreads();

  // ---- last block deterministically sums the 256 loss partials ----
  if (lastf) {
    float v = (tid < NBLKS) ? ldg1(&lpart[tid]) : 0.f;
#pragma unroll
    for (int msk = 32; msk; msk >>= 1) v += __shfl_down(v, msk, 64);
    if (tid < NBLKS && (tid & 63) == 0) lsum[tid >> 6] = v;
    __syncthreads();
    if (tid == 0) {
      float s = 0.f;
#pragma unroll
      for (int k2 = 0; k2 < 4; ++k2) s += lsum[k2];
      out[0] = s / (float)N;
    }
  }
}

extern "C" void kernel_launch(void* const* d_in, const int* in_sizes, int n_in,
                              void* d_out, int out_size, void* d_ws, size_t ws_size,
                              hipStream_t stream)
{
  (void)in_sizes; (void)n_in; (void)out_size; (void)ws_size;
  const float* x    = (const float*)d_in[0];
  const int*   tgt  = (const int*)d_in[1];
  const float* marg = (const float*)d_in[2];
  const float* wgt  = (const float*)d_in[3];
  const int*   hm   = (const int*)d_in[4];
  float* out = (float*)d_out;

  ushort*   xf    = (ushort*)d_ws;                          // 1 MB fragment-linear bf16-hi
  float*    lpart = (float*)((char*)d_ws + (1 << 20));      // 256 loss partials
  unsigned* done  = (unsigned*)(lpart + NBLKS);             // 1 counter

  k_conv<<<256, 256, 0, stream>>>(x, xf, done);
  k_main<<<NBLKS, 1024, 0, stream>>>(x, tgt, marg, wgt, hm, out, xf, lpart, done);
}